// Round 4
// baseline (1139.868 us; speedup 1.0000x reference)
//
#include <hip/hip_runtime.h>
#include <hip/hip_fp16.h>

#define NN 100000
#define NE 1600000
#define NB 391   // ceil(NN/256)

// ============================ CSR build ============================

__global__ __launch_bounds__(256) void hist_k(const int* __restrict__ ei,
                                              int* __restrict__ deg) {
    int e = blockIdx.x * 256 + threadIdx.x;
    atomicAdd(&deg[ei[NE + e]], 1);
}

__global__ __launch_bounds__(256) void scan1_k(const int* __restrict__ deg,
                                               int* __restrict__ scanned,
                                               int* __restrict__ bsums) {
    __shared__ int tmp[256];
    int i = blockIdx.x * 256 + threadIdx.x;
    int v = (i < NN) ? deg[i] : 0;
    tmp[threadIdx.x] = v;
    __syncthreads();
#pragma unroll
    for (int off = 1; off < 256; off <<= 1) {
        int t = (threadIdx.x >= off) ? tmp[threadIdx.x - off] : 0;
        __syncthreads();
        tmp[threadIdx.x] += t;
        __syncthreads();
    }
    if (i < NN) scanned[i] = tmp[threadIdx.x];
    if (threadIdx.x == 255) bsums[blockIdx.x] = tmp[255];
}

__global__ __launch_bounds__(512) void scan2_k(int* __restrict__ bsums) {
    __shared__ int tmp[512];
    int v = (threadIdx.x < NB) ? bsums[threadIdx.x] : 0;
    tmp[threadIdx.x] = v;
    __syncthreads();
#pragma unroll
    for (int off = 1; off < 512; off <<= 1) {
        int t = (threadIdx.x >= off) ? tmp[threadIdx.x - off] : 0;
        __syncthreads();
        tmp[threadIdx.x] += t;
        __syncthreads();
    }
    if (threadIdx.x < NB) bsums[threadIdx.x] = tmp[threadIdx.x];
}

__global__ __launch_bounds__(256) void scan3_k(const int* __restrict__ scanned,
                                               const int* __restrict__ bsums,
                                               const int* __restrict__ deg,
                                               int* __restrict__ rowptr,
                                               int* __restrict__ cursor) {
    int i = blockIdx.x * 256 + threadIdx.x;
    if (i < NN) {
        int incl = scanned[i] + (blockIdx.x ? bsums[blockIdx.x - 1] : 0);
        rowptr[i + 1] = incl;
        cursor[i] = incl - deg[i];
        if (i == 0) rowptr[0] = 0;
    }
}

__global__ __launch_bounds__(256) void fill_k(const int* __restrict__ ei,
                                              int* __restrict__ cursor,
                                              int* __restrict__ col) {
    int e = blockIdx.x * 256 + threadIdx.x;
    int dst = ei[NE + e];
    int pos = atomicAdd(&cursor[dst], 1);
    col[pos] = ei[e];
}

// ---- x (f32) -> x16 (fp16), packed ----
__global__ __launch_bounds__(256) void cvt_k(const float* __restrict__ x,
                                             __half* __restrict__ x16) {
    int i = blockIdx.x * 256 + threadIdx.x;
    if (i < NN * 32) x16[i] = __float2half(x[i]);
}

// ============ layer 1: gather(x16) + relu(relu((agg+x)W1+b1)W2+b2) ============
// lane = (edge-group g: lane>>4) x (channel-pair cp: lane&15); half2 loads,
// 64B (one line) per edge; 4 groups x 4-deep unroll = 16 edges in flight/wave.
__global__ __launch_bounds__(256, 6) void fused1(const float* __restrict__ x,
                                                 const __half2* __restrict__ x16,
                                                 const int* __restrict__ rowptr,
                                                 const int* __restrict__ col,
                                                 const float* __restrict__ W1,
                                                 const float* __restrict__ b1,
                                                 const float* __restrict__ W2,
                                                 const float* __restrict__ b2,
                                                 __half* __restrict__ h16) {
    __shared__ float W1s[32 * 64];
    __shared__ float W2s[64 * 64];
    __shared__ float b1s[64];
    __shared__ float b2s[64];
    for (int i = threadIdx.x; i < 32 * 64; i += 256) W1s[i] = W1[i];
    for (int i = threadIdx.x; i < 64 * 64; i += 256) W2s[i] = W2[i];
    if (threadIdx.x < 64) {
        b1s[threadIdx.x] = b1[threadIdx.x];
        b2s[threadIdx.x] = b2[threadIdx.x];
    }
    __syncthreads();

    int lane = threadIdx.x & 63;
    int g = lane >> 4;       // edge group (0..3)
    int cp = lane & 15;      // channel pair -> channels 2cp, 2cp+1
    int gw = blockIdx.x * 4 + (threadIdx.x >> 6);
    int nwaves = gridDim.x * 4;

    for (int node = gw; node < NN; node += nwaves) {
        int s0 = rowptr[node], s1 = rowptr[node + 1];
        float self = x[(size_t)node * 32 + (lane & 31)];

        float ax0 = 0.f, ax1 = 0.f, ax2 = 0.f, ax3 = 0.f;
        float ay0 = 0.f, ay1 = 0.f, ay2 = 0.f, ay3 = 0.f;
        int e = s0 + g;
        for (; e + 12 < s1; e += 16) {
            int c0 = col[e], c1 = col[e + 4], c2 = col[e + 8], c3 = col[e + 12];
            float2 f0 = __half22float2(x16[(size_t)c0 * 16 + cp]);
            float2 f1 = __half22float2(x16[(size_t)c1 * 16 + cp]);
            float2 f2 = __half22float2(x16[(size_t)c2 * 16 + cp]);
            float2 f3 = __half22float2(x16[(size_t)c3 * 16 + cp]);
            ax0 += f0.x; ay0 += f0.y;
            ax1 += f1.x; ay1 += f1.y;
            ax2 += f2.x; ay2 += f2.y;
            ax3 += f3.x; ay3 += f3.y;
        }
        for (; e < s1; e += 4) {
            float2 f = __half22float2(x16[(size_t)col[e] * 16 + cp]);
            ax0 += f.x; ay0 += f.y;
        }
        float ax = (ax0 + ax1) + (ax2 + ax3);
        float ay = (ay0 + ay1) + (ay2 + ay3);
        ax += __shfl_xor(ax, 16); ax += __shfl_xor(ax, 32);
        ay += __shfl_xor(ay, 16); ay += __shfl_xor(ay, 32);
        // redistribute: channel c = lane&31 lives in lane c>>1 (x=even ch, y=odd)
        float lo = __shfl(ax, (lane & 31) >> 1);
        float hi = __shfl(ay, (lane & 31) >> 1);
        float aval = ((lane & 1) ? hi : lo) + self;

        float s = b1s[lane];
#pragma unroll
        for (int i = 0; i < 32; ++i)
            s += __shfl(aval, i) * W1s[i * 64 + lane];
        float t = fmaxf(s, 0.f);

        float s2 = b2s[lane];
#pragma unroll
        for (int j = 0; j < 64; ++j)
            s2 += __shfl(t, j) * W2s[j * 64 + lane];
        h16[(size_t)node * 64 + lane] = __float2half(fmaxf(s2, 0.f));
    }
}

// ============ layer 2: gather(h16) + relu((agg+h)W3+b3)W4+b4 ============
// lane = (parity p: lane>>5) x (channel-pair cp: lane&31); 128B per edge;
// 2 parities x 4-deep unroll = 8 edges in flight/wave.
__global__ __launch_bounds__(256, 6) void fused2(const __half2* __restrict__ h2,
                                                 const __half* __restrict__ h16,
                                                 const int* __restrict__ rowptr,
                                                 const int* __restrict__ col,
                                                 const float* __restrict__ W3,
                                                 const float* __restrict__ b3,
                                                 const float* __restrict__ W4,
                                                 const float* __restrict__ b4,
                                                 float* __restrict__ out) {
    __shared__ float W3s[64 * 64];
    __shared__ float W4s[64 * 32];
    __shared__ float b3s[64];
    __shared__ float b4s[32];
    for (int i = threadIdx.x; i < 64 * 64; i += 256) W3s[i] = W3[i];
    for (int i = threadIdx.x; i < 64 * 32; i += 256) W4s[i] = W4[i];
    if (threadIdx.x < 64) b3s[threadIdx.x] = b3[threadIdx.x];
    if (threadIdx.x < 32) b4s[threadIdx.x] = b4[threadIdx.x];
    __syncthreads();

    int lane = threadIdx.x & 63;
    int p = lane >> 5;       // edge parity
    int cp = lane & 31;      // channel pair -> channels 2cp, 2cp+1
    int gw = blockIdx.x * 4 + (threadIdx.x >> 6);
    int nwaves = gridDim.x * 4;

    for (int node = gw; node < NN; node += nwaves) {
        int s0 = rowptr[node], s1 = rowptr[node + 1];
        float self = __half2float(h16[(size_t)node * 64 + lane]);

        float ax0 = 0.f, ax1 = 0.f, ax2 = 0.f, ax3 = 0.f;
        float ay0 = 0.f, ay1 = 0.f, ay2 = 0.f, ay3 = 0.f;
        int e = s0 + p;
        for (; e + 6 < s1; e += 8) {
            int c0 = col[e], c1 = col[e + 2], c2 = col[e + 4], c3 = col[e + 6];
            float2 f0 = __half22float2(h2[(size_t)c0 * 32 + cp]);
            float2 f1 = __half22float2(h2[(size_t)c1 * 32 + cp]);
            float2 f2 = __half22float2(h2[(size_t)c2 * 32 + cp]);
            float2 f3 = __half22float2(h2[(size_t)c3 * 32 + cp]);
            ax0 += f0.x; ay0 += f0.y;
            ax1 += f1.x; ay1 += f1.y;
            ax2 += f2.x; ay2 += f2.y;
            ax3 += f3.x; ay3 += f3.y;
        }
        for (; e < s1; e += 2) {
            float2 f = __half22float2(h2[(size_t)col[e] * 32 + cp]);
            ax0 += f.x; ay0 += f.y;
        }
        float ax = (ax0 + ax1) + (ax2 + ax3);
        float ay = (ay0 + ay1) + (ay2 + ay3);
        ax += __shfl_xor(ax, 32);
        ay += __shfl_xor(ay, 32);
        // channel c = lane lives in lane c>>1 (x=even, y=odd)
        float lo = __shfl(ax, lane >> 1);
        float hi = __shfl(ay, lane >> 1);
        float aval = ((lane & 1) ? hi : lo) + self;

        float s = b3s[lane];
#pragma unroll
        for (int i = 0; i < 64; ++i)
            s += __shfl(aval, i) * W3s[i * 64 + lane];
        float t = fmaxf(s, 0.f);

        float s2 = b4s[lane & 31];
#pragma unroll
        for (int j = 0; j < 64; ++j)
            s2 += __shfl(t, j) * W4s[j * 32 + (lane & 31)];
        if (lane < 32) out[(size_t)node * 32 + lane] = s2;
    }
}

extern "C" void kernel_launch(void* const* d_in, const int* in_sizes, int n_in,
                              void* d_out, int out_size, void* d_ws, size_t ws_size,
                              hipStream_t stream) {
    const float* x  = (const float*)d_in[0];
    const int*   ei = (const int*)d_in[1];
    const float* W1 = (const float*)d_in[2];
    const float* b1 = (const float*)d_in[3];
    const float* W2 = (const float*)d_in[4];
    const float* b2 = (const float*)d_in[5];
    const float* W3 = (const float*)d_in[6];
    const float* b3 = (const float*)d_in[7];
    const float* W4 = (const float*)d_in[8];
    const float* b4 = (const float*)d_in[9];
    float* out = (float*)d_out;

    char* ws = (char*)d_ws;
    __half* h16   = (__half*)ws;                                  ws += (size_t)NN * 64 * 2;  // 12.8 MB
    __half* x16   = (__half*)ws;                                  ws += (size_t)NN * 32 * 2;  // 6.4 MB
    int*   col    = (int*)ws;                                     ws += (size_t)NE * 4;       // 6.4 MB
    int*   deg    = (int*)ws;                                     ws += (size_t)NN * 4;
    int*   scanned= (int*)ws;                                     ws += (size_t)NN * 4;
    int*   rowptr = (int*)ws;                                     ws += (size_t)(NN + 1) * 4;
    int*   cursor = (int*)ws;                                     ws += (size_t)NN * 4;
    int*   bsums  = (int*)ws;                                     ws += (size_t)NB * 4;

    // ---- CSR build + fp16 conversion ----
    hipMemsetAsync(deg, 0, (size_t)NN * 4, stream);
    cvt_k<<<(NN * 32 + 255) / 256, 256, 0, stream>>>(x, x16);
    hist_k<<<NE / 256, 256, 0, stream>>>(ei, deg);
    scan1_k<<<NB, 256, 0, stream>>>(deg, scanned, bsums);
    scan2_k<<<1, 512, 0, stream>>>(bsums);
    scan3_k<<<NB, 256, 0, stream>>>(scanned, bsums, deg, rowptr, cursor);
    fill_k<<<NE / 256, 256, 0, stream>>>(ei, cursor, col);

    // ---- fused layers ----
    fused1<<<1536, 256, 0, stream>>>(x, (const __half2*)x16, rowptr, col,
                                     W1, b1, W2, b2, h16);
    fused2<<<1536, 256, 0, stream>>>((const __half2*)h16, h16, rowptr, col,
                                     W3, b3, W4, b4, out);
}

// Round 5
// 1036.285 us; speedup vs baseline: 1.1000x; 1.1000x over previous
//
#include <hip/hip_runtime.h>

#define NN 100000
#define NE 1600000
#define NB 391        // ceil(NN/256)
#define NS 13         // source slices: slice = src >> 13 (8192 nodes/slice)
#define NSP1 14
#define NPW 25        // nodes per wave
#define SLICE_SHIFT 13

// ============================ CSR build (slice-bucketed) ============================

__global__ __launch_bounds__(256) void hist2_k(const int* __restrict__ ei,
                                               int* __restrict__ deg2) {
    int e = blockIdx.x * 256 + threadIdx.x;
    int src = ei[e];
    int dst = ei[NE + e];
    atomicAdd(&deg2[dst * NS + (src >> SLICE_SHIFT)], 1);
}

__global__ __launch_bounds__(256) void rowsum_k(const int* __restrict__ deg2,
                                                int* __restrict__ deg) {
    int i = blockIdx.x * 256 + threadIdx.x;
    if (i < NN) {
        int s = 0;
#pragma unroll
        for (int k = 0; k < NS; ++k) s += deg2[i * NS + k];
        deg[i] = s;
    }
}

__global__ __launch_bounds__(256) void scan1_k(const int* __restrict__ deg,
                                               int* __restrict__ scanned,
                                               int* __restrict__ bsums) {
    __shared__ int tmp[256];
    int i = blockIdx.x * 256 + threadIdx.x;
    int v = (i < NN) ? deg[i] : 0;
    tmp[threadIdx.x] = v;
    __syncthreads();
#pragma unroll
    for (int off = 1; off < 256; off <<= 1) {
        int t = (threadIdx.x >= off) ? tmp[threadIdx.x - off] : 0;
        __syncthreads();
        tmp[threadIdx.x] += t;
        __syncthreads();
    }
    if (i < NN) scanned[i] = tmp[threadIdx.x];
    if (threadIdx.x == 255) bsums[blockIdx.x] = tmp[255];
}

__global__ __launch_bounds__(512) void scan2_k(int* __restrict__ bsums) {
    __shared__ int tmp[512];
    int v = (threadIdx.x < NB) ? bsums[threadIdx.x] : 0;
    tmp[threadIdx.x] = v;
    __syncthreads();
#pragma unroll
    for (int off = 1; off < 512; off <<= 1) {
        int t = (threadIdx.x >= off) ? tmp[threadIdx.x - off] : 0;
        __syncthreads();
        tmp[threadIdx.x] += t;
        __syncthreads();
    }
    if (threadIdx.x < NB) bsums[threadIdx.x] = tmp[threadIdx.x];
}

// P[n*NSP1+0] = row start (stable); P[n*NSP1+s+1] = start of bucket s (fill cursor).
// After fill2_k, P[n*NSP1+s+1] == end of bucket s, so bucket s = [P[n][s], P[n][s+1]).
__global__ __launch_bounds__(256) void scan3b_k(const int* __restrict__ scanned,
                                                const int* __restrict__ bsums,
                                                const int* __restrict__ deg,
                                                const int* __restrict__ deg2,
                                                int* __restrict__ P) {
    int i = blockIdx.x * 256 + threadIdx.x;
    if (i < NN) {
        int incl = scanned[i] + (blockIdx.x ? bsums[blockIdx.x - 1] : 0);
        int run = incl - deg[i];
        P[i * NSP1 + 0] = run;
#pragma unroll
        for (int s = 0; s < NS; ++s) {
            P[i * NSP1 + s + 1] = run;
            run += deg2[i * NS + s];
        }
    }
}

__global__ __launch_bounds__(256) void fill2_k(const int* __restrict__ ei,
                                               int* __restrict__ P,
                                               int* __restrict__ col) {
    int e = blockIdx.x * 256 + threadIdx.x;
    int src = ei[e];
    int dst = ei[NE + e];
    int pos = atomicAdd(&P[dst * NSP1 + (src >> SLICE_SHIFT) + 1], 1);
    col[pos] = src;
}

// ============ layer 1: slice-synchronous gather(x) + MLP1 -> h ============
// wave owns NPW nodes; acc[NPW] in registers across the slice loop.
// lanes 0-31 / 32-63 take alternate edges of the same node; channel c = lane&31.
__global__ __launch_bounds__(256, 4) void fused1s(const float* __restrict__ x,
                                                  const int* __restrict__ P,
                                                  const int* __restrict__ col,
                                                  const float* __restrict__ W1,
                                                  const float* __restrict__ b1,
                                                  const float* __restrict__ W2,
                                                  const float* __restrict__ b2,
                                                  float* __restrict__ h) {
    __shared__ float W1s[32 * 64];
    __shared__ float W2s[64 * 64];
    __shared__ float b1s[64];
    __shared__ float b2s[64];
    for (int i = threadIdx.x; i < 32 * 64; i += 256) W1s[i] = W1[i];
    for (int i = threadIdx.x; i < 64 * 64; i += 256) W2s[i] = W2[i];
    if (threadIdx.x < 64) {
        b1s[threadIdx.x] = b1[threadIdx.x];
        b2s[threadIdx.x] = b2[threadIdx.x];
    }
    __syncthreads();

    int lane = threadIdx.x & 63;
    int c = lane & 31;
    int p = lane >> 5;
    int gw = blockIdx.x * 4 + (threadIdx.x >> 6);
    int base = gw * NPW;

    float acc[NPW];
#pragma unroll
    for (int k = 0; k < NPW; ++k) acc[k] = 0.f;

    for (int s = 0; s < NS; ++s) {
#pragma unroll
        for (int k = 0; k < NPW; ++k) {
            int n = base + k;
            if (n < NN) {
                int e0 = P[n * NSP1 + s];
                int e1 = P[n * NSP1 + s + 1];
                float a = acc[k];
                for (int e = e0 + p; e < e1; e += 2)
                    a += x[(size_t)col[e] * 32 + c];
                acc[k] = a;
            }
        }
    }

    for (int k = 0; k < NPW; ++k) {
        int n = base + k;
        if (n >= NN) break;
        float av = acc[0];
#pragma unroll
        for (int kk = 1; kk < NPW; ++kk)
            if (kk == k) av = acc[kk];          // static-index select (rule #20)
        av += __shfl_xor(av, 32);               // fold edge-parity halves
        float aval = av + x[(size_t)n * 32 + c];

        float sv = b1s[lane];
#pragma unroll
        for (int i = 0; i < 32; ++i)
            sv += __shfl(aval, i) * W1s[i * 64 + lane];
        float t = fmaxf(sv, 0.f);

        float s2 = b2s[lane];
#pragma unroll
        for (int j = 0; j < 64; ++j)
            s2 += __shfl(t, j) * W2s[j * 64 + lane];
        h[(size_t)n * 64 + lane] = fmaxf(s2, 0.f);
    }
}

// ============ layer 2: slice-synchronous gather(h) + MLP2 -> out ============
__global__ __launch_bounds__(256, 4) void fused2s(const float* __restrict__ h,
                                                  const int* __restrict__ P,
                                                  const int* __restrict__ col,
                                                  const float* __restrict__ W3,
                                                  const float* __restrict__ b3,
                                                  const float* __restrict__ W4,
                                                  const float* __restrict__ b4,
                                                  float* __restrict__ out) {
    __shared__ float W3s[64 * 64];
    __shared__ float W4s[64 * 32];
    __shared__ float b3s[64];
    __shared__ float b4s[32];
    for (int i = threadIdx.x; i < 64 * 64; i += 256) W3s[i] = W3[i];
    for (int i = threadIdx.x; i < 64 * 32; i += 256) W4s[i] = W4[i];
    if (threadIdx.x < 64) b3s[threadIdx.x] = b3[threadIdx.x];
    if (threadIdx.x < 32) b4s[threadIdx.x] = b4[threadIdx.x];
    __syncthreads();

    int lane = threadIdx.x & 63;
    int gw = blockIdx.x * 4 + (threadIdx.x >> 6);
    int base = gw * NPW;

    float acc[NPW];
#pragma unroll
    for (int k = 0; k < NPW; ++k) acc[k] = 0.f;

    for (int s = 0; s < NS; ++s) {
#pragma unroll
        for (int k = 0; k < NPW; ++k) {
            int n = base + k;
            if (n < NN) {
                int e0 = P[n * NSP1 + s];
                int e1 = P[n * NSP1 + s + 1];
                float a = acc[k];
                for (int e = e0; e < e1; ++e)
                    a += h[(size_t)col[e] * 64 + lane];
                acc[k] = a;
            }
        }
    }

    for (int k = 0; k < NPW; ++k) {
        int n = base + k;
        if (n >= NN) break;
        float av = acc[0];
#pragma unroll
        for (int kk = 1; kk < NPW; ++kk)
            if (kk == k) av = acc[kk];
        float aval = av + h[(size_t)n * 64 + lane];

        float sv = b3s[lane];
#pragma unroll
        for (int i = 0; i < 64; ++i)
            sv += __shfl(aval, i) * W3s[i * 64 + lane];
        float t = fmaxf(sv, 0.f);

        float s2 = b4s[lane & 31];
#pragma unroll
        for (int j = 0; j < 64; ++j)
            s2 += __shfl(t, j) * W4s[j * 32 + (lane & 31)];
        if (lane < 32) out[(size_t)n * 32 + lane] = s2;
    }
}

extern "C" void kernel_launch(void* const* d_in, const int* in_sizes, int n_in,
                              void* d_out, int out_size, void* d_ws, size_t ws_size,
                              hipStream_t stream) {
    const float* x  = (const float*)d_in[0];
    const int*   ei = (const int*)d_in[1];
    const float* W1 = (const float*)d_in[2];
    const float* b1 = (const float*)d_in[3];
    const float* W2 = (const float*)d_in[4];
    const float* b2 = (const float*)d_in[5];
    const float* W3 = (const float*)d_in[6];
    const float* b3 = (const float*)d_in[7];
    const float* W4 = (const float*)d_in[8];
    const float* b4 = (const float*)d_in[9];
    float* out = (float*)d_out;

    char* ws = (char*)d_ws;
    float* h   = (float*)ws;                          ws += (size_t)NN * 64 * 4;       // 25.6 MB
    int*   col = (int*)ws;                            ws += (size_t)NE * 4;            // 6.4 MB
    int*   P   = (int*)ws;                            ws += (size_t)NN * NSP1 * 4;     // 5.6 MB

    // build-time arrays overlay the h region (dead before fused1s writes h)
    char* ov = (char*)h;
    int* deg2    = (int*)ov;                          ov += (size_t)NN * NS * 4;       // 5.2 MB
    int* deg     = (int*)ov;                          ov += (size_t)NN * 4;
    int* scanned = (int*)ov;                          ov += (size_t)NN * 4;
    int* bsums   = (int*)ov;                          ov += (size_t)NB * 4;

    // ---- slice-bucketed CSR build ----
    hipMemsetAsync(deg2, 0, (size_t)NN * NS * 4, stream);
    hist2_k<<<NE / 256, 256, 0, stream>>>(ei, deg2);
    rowsum_k<<<NB, 256, 0, stream>>>(deg2, deg);
    scan1_k<<<NB, 256, 0, stream>>>(deg, scanned, bsums);
    scan2_k<<<1, 512, 0, stream>>>(bsums);
    scan3b_k<<<NB, 256, 0, stream>>>(scanned, bsums, deg, deg2, P);
    fill2_k<<<NE / 256, 256, 0, stream>>>(ei, P, col);

    // ---- slice-synchronous fused layers (1024 blocks = 4/CU, all co-resident) ----
    fused1s<<<1024, 256, 0, stream>>>(x, P, col, W1, b1, W2, b2, h);
    fused2s<<<1024, 256, 0, stream>>>(h, P, col, W3, b3, W4, b4, out);
}